// Round 1
// baseline (545.618 us; speedup 1.0000x reference)
//
#include <hip/hip_runtime.h>

#define N_ATOMS 8192
#define DIM 64
#define N_MOL 256
#define N_LAYERS 3
#define BM 64     // m-chunk staged in LDS
#define MS 4      // m-splits (grid.y)

// ---------------- embed: v[n][d] = table[fp[n]][d] ----------------
__global__ void embed_kernel(const int* __restrict__ fp,
                             const float* __restrict__ table,
                             float* __restrict__ v) {
    int n = blockIdx.x;
    int d = threadIdx.x;
    v[n * DIM + d] = table[fp[n] * DIM + d];
}

// ------ linear+relu: h[n][e] = relu(b[e] + sum_d v[n][d]*W[e][d]); vnew = h ------
__global__ __launch_bounds__(256) void linear_relu_kernel(
        const float* __restrict__ v, const float* __restrict__ W,
        const float* __restrict__ b, float* __restrict__ h,
        float* __restrict__ vnew) {
    __shared__ float Ws[DIM][DIM + 1];   // pad 65: lanes e differ -> (e+d)%32, 2-way max
    __shared__ float vs[4][DIM];
    int t = threadIdx.x;
    for (int i = t; i < DIM * DIM; i += 256) Ws[i >> 6][i & 63] = W[i];
    int n0 = blockIdx.x * 4;
    {
        int r = t >> 6, d = t & 63;
        vs[r][d] = v[(n0 + r) * DIM + d];
    }
    __syncthreads();
    int r = t >> 6, e = t & 63;
    float acc = b[e];
#pragma unroll
    for (int d = 0; d < DIM; ++d) acc += vs[r][d] * Ws[e][d];
    acc = acc > 0.f ? acc : 0.f;
    int idx = (n0 + r) * DIM + e;
    h[idx] = acc;
    vnew[idx] = acc;
}

// ------ vnew[r][c] += sum_{m in split} A[r][m] * h[m][c]  (vnew pre-set to h) ------
__global__ __launch_bounds__(256) void matmul_acc_kernel(
        const float* __restrict__ A, const float* __restrict__ h,
        float* __restrict__ vnew) {
    __shared__ float As[64][BM + 1];     // pad 65
    __shared__ float hs[BM][DIM + 4];    // pad 68: keeps float4 alignment (272B rows)

    const int t  = threadIdx.x;
    const int tx = t & 15;               // col group: cols tx*4..+3
    const int ty = t >> 4;               // row group: rows ty*4..+3
    const int r0 = blockIdx.x * 64;
    const int m_base = blockIdx.y * (N_ATOMS / MS);
    const int nchunk = (N_ATOMS / MS) / BM;

    float c_[4][4];
#pragma unroll
    for (int i = 0; i < 4; ++i)
#pragma unroll
        for (int j = 0; j < 4; ++j) c_[i][j] = 0.f;

    for (int mc = 0; mc < nchunk; ++mc) {
        const int m0 = m_base + mc * BM;
        // stage A tile (64 rows x BM) and h tile (BM x 64), coalesced float4 loads
        {
            const int rr = t >> 4;       // 0..15
            const int mq = t & 15;       // 0..15
#pragma unroll
            for (int k = 0; k < 4; ++k) {
                const int r = rr + 16 * k;
                const float4 av = *(const float4*)&A[(size_t)(r0 + r) * N_ATOMS + m0 + mq * 4];
                As[r][mq * 4 + 0] = av.x;
                As[r][mq * 4 + 1] = av.y;
                As[r][mq * 4 + 2] = av.z;
                As[r][mq * 4 + 3] = av.w;
                const float4 hv = *(const float4*)&h[(size_t)(m0 + r) * DIM + mq * 4];
                hs[r][mq * 4 + 0] = hv.x;
                hs[r][mq * 4 + 1] = hv.y;
                hs[r][mq * 4 + 2] = hv.z;
                hs[r][mq * 4 + 3] = hv.w;
            }
        }
        __syncthreads();
#pragma unroll 16
        for (int mm = 0; mm < BM; ++mm) {
            const float a0 = As[ty * 4 + 0][mm];
            const float a1 = As[ty * 4 + 1][mm];
            const float a2 = As[ty * 4 + 2][mm];
            const float a3 = As[ty * 4 + 3][mm];
            const float4 hv = *(const float4*)&hs[mm][tx * 4];
            c_[0][0] += a0 * hv.x; c_[0][1] += a0 * hv.y; c_[0][2] += a0 * hv.z; c_[0][3] += a0 * hv.w;
            c_[1][0] += a1 * hv.x; c_[1][1] += a1 * hv.y; c_[1][2] += a1 * hv.z; c_[1][3] += a1 * hv.w;
            c_[2][0] += a2 * hv.x; c_[2][1] += a2 * hv.y; c_[2][2] += a2 * hv.z; c_[2][3] += a2 * hv.w;
            c_[3][0] += a3 * hv.x; c_[3][1] += a3 * hv.y; c_[3][2] += a3 * hv.z; c_[3][3] += a3 * hv.w;
        }
        __syncthreads();
    }
#pragma unroll
    for (int i = 0; i < 4; ++i)
#pragma unroll
        for (int j = 0; j < 4; ++j)
            atomicAdd(&vnew[(size_t)(r0 + ty * 4 + i) * DIM + tx * 4 + j], c_[i][j]);
}

// ------ segment sum: out[m][d] = sum_{n: seg[n]==m} v[n][d]  (seg sorted) ------
__device__ __forceinline__ int lower_bound_dev(const int* __restrict__ seg, int val) {
    int lo = 0, hi = N_ATOMS;
    while (lo < hi) {
        int mid = (lo + hi) >> 1;
        if (seg[mid] < val) lo = mid + 1; else hi = mid;
    }
    return lo;
}

__global__ void segsum_kernel(const float* __restrict__ v,
                              const int* __restrict__ seg,
                              float* __restrict__ out) {
    int m = blockIdx.x;
    int d = threadIdx.x;  // 64
    int lo = lower_bound_dev(seg, m);
    int hi = lower_bound_dev(seg, m + 1);
    float acc = 0.f;
    for (int n = lo; n < hi; ++n) acc += v[n * DIM + d];
    out[m * DIM + d] = acc;
}

extern "C" void kernel_launch(void* const* d_in, const int* in_sizes, int n_in,
                              void* d_out, int out_size, void* d_ws, size_t ws_size,
                              hipStream_t stream) {
    const int*   fp    = (const int*)d_in[0];
    const float* A     = (const float*)d_in[1];
    const int*   seg   = (const int*)d_in[2];
    const float* table = (const float*)d_in[3];
    const float* W     = (const float*)d_in[4];
    const float* b     = (const float*)d_in[5];
    float* out = (float*)d_out;

    float* v0 = (float*)d_ws;
    float* v1 = v0 + N_ATOMS * DIM;
    float* h  = v1 + N_ATOMS * DIM;

    embed_kernel<<<N_ATOMS, DIM, 0, stream>>>(fp, table, v0);

    float* vcur = v0;
    float* vnext = v1;
    for (int l = 0; l < N_LAYERS; ++l) {
        linear_relu_kernel<<<N_ATOMS / 4, 256, 0, stream>>>(
            vcur, W + l * DIM * DIM, b + l * DIM, h, vnext);
        dim3 grid(N_ATOMS / 64, MS);
        matmul_acc_kernel<<<grid, 256, 0, stream>>>(A, h, vnext);
        float* tmp = vcur; vcur = vnext; vnext = tmp;
    }

    segsum_kernel<<<N_MOL, DIM, 0, stream>>>(vcur, seg, out);
}

// Round 2
// 330.460 us; speedup vs baseline: 1.6511x; 1.6511x over previous
//
#include <hip/hip_runtime.h>

#define N_ATOMS 8192
#define DIM 64
#define N_MOL 256
#define N_LAYERS 3
#define KS 16
#define KCH (N_ATOMS / KS)   // 512 k per block

typedef __attribute__((ext_vector_type(8))) short short8v;
typedef __attribute__((ext_vector_type(4))) float f32x4;
typedef unsigned short ushort_t;

// f32 -> bf16 RTNE (no NaN handling needed: inputs are finite)
__device__ __forceinline__ ushort_t f2bf(float x) {
    unsigned u = __float_as_uint(x);
    u += 0x7fffu + ((u >> 16) & 1u);
    return (ushort_t)(u >> 16);
}

// ---------------- embed: v[n][d] = table[fp[n]][d] ----------------
__global__ void embed_kernel(const int* __restrict__ fp,
                             const float* __restrict__ table,
                             float* __restrict__ v) {
    int n = blockIdx.x;
    int d = threadIdx.x;
    v[n * DIM + d] = table[fp[n] * DIM + d];
}

// ---- linear+relu over 64 atoms/block; writes vnext (f32, residual init = h)
// ---- and hT (bf16, [DIM][N_ATOMS]) for the MFMA B-operand ----
__global__ __launch_bounds__(256) void linear_relu_T_kernel(
        const float* __restrict__ v, const float* __restrict__ W,
        const float* __restrict__ b, float* __restrict__ vnext,
        ushort_t* __restrict__ hT) {
    __shared__ float Ws[DIM][DIM + 1];   // [e][d], (65e+d)%32 -> 2-way max (free)
    __shared__ float vsT[DIM][68];       // [d][n], pad 68 keeps 16B align + broadcast reads

    const int t = threadIdx.x;
    const int n0 = blockIdx.x * 64;
    for (int i = t; i < DIM * DIM; i += 256) {
        Ws[i >> 6][i & 63] = W[i];
        float val = v[n0 * DIM + i];         // n = n0 + (i>>6), d = i&63
        vsT[i & 63][i >> 6] = val;
    }
    __syncthreads();

    const int e = t & 63;        // feature (lane)
    const int g = t >> 6;        // atom quarter (wave)
    float acc[16];
    const float be = b[e];
#pragma unroll
    for (int i = 0; i < 16; ++i) acc[i] = be;

    for (int d = 0; d < DIM; ++d) {
        const float w = Ws[e][d];
        const float4* vp = (const float4*)&vsT[d][g * 16];
        float4 x0 = vp[0], x1 = vp[1], x2 = vp[2], x3 = vp[3];
        acc[0]  += w * x0.x; acc[1]  += w * x0.y; acc[2]  += w * x0.z; acc[3]  += w * x0.w;
        acc[4]  += w * x1.x; acc[5]  += w * x1.y; acc[6]  += w * x1.z; acc[7]  += w * x1.w;
        acc[8]  += w * x2.x; acc[9]  += w * x2.y; acc[10] += w * x2.z; acc[11] += w * x2.w;
        acc[12] += w * x3.x; acc[13] += w * x3.y; acc[14] += w * x3.z; acc[15] += w * x3.w;
    }

    ushort_t hb[16];
#pragma unroll
    for (int i = 0; i < 16; ++i) {
        float hv = acc[i] > 0.f ? acc[i] : 0.f;
        const int n = n0 + g * 16 + i;
        vnext[(size_t)n * DIM + e] = hv;     // coalesced: lanes span e
        hb[i] = f2bf(hv);
    }
    // hT[e][n0 + g*16 .. +15]: 32B contiguous per thread
    ushort_t* hp = hT + (size_t)e * N_ATOMS + n0 + g * 16;
    *(short8v*)(hp)     = *(short8v*)&hb[0];
    *(short8v*)(hp + 8) = *(short8v*)&hb[8];
}

// ---- vnext += A @ h via MFMA; A read f32 and converted in-register ----
// grid: (N_ATOMS/64 row-blocks, KS k-splits), 256 threads = 4 waves.
// wave w owns rows [bx*64 + w*16, +16), all 64 cols (4 col-tiles of 16).
__global__ __launch_bounds__(256) void matmul_mfma_kernel(
        const float* __restrict__ A, const ushort_t* __restrict__ hT,
        float* __restrict__ vnext) {
    const int t  = threadIdx.x;
    const int w  = t >> 6;
    const int l  = t & 63;
    const int lm = l & 15;               // M-row (A frag) / N-col (B frag) in tile
    const int lk = (l >> 4) << 3;        // k base: 0,8,16,24
    const size_t row = (size_t)blockIdx.x * 64 + w * 16 + lm;
    const size_t kc0 = (size_t)blockIdx.y * KCH;

    const float*    ap  = A  + row * N_ATOMS + kc0 + lk;
    const ushort_t* bp0 = hT + (size_t)lm * N_ATOMS + kc0 + lk;
    const ushort_t* bp1 = bp0 + (size_t)16 * N_ATOMS;
    const ushort_t* bp2 = bp0 + (size_t)32 * N_ATOMS;
    const ushort_t* bp3 = bp0 + (size_t)48 * N_ATOMS;

    f32x4 acc0 = {0.f, 0.f, 0.f, 0.f};
    f32x4 acc1 = acc0, acc2 = acc0, acc3 = acc0;

#pragma unroll 2
    for (int kk = 0; kk < KCH; kk += 32) {
        float4 a0 = *(const float4*)(ap + kk);
        float4 a1 = *(const float4*)(ap + kk + 4);
        short8v b0 = *(const short8v*)(bp0 + kk);
        short8v b1 = *(const short8v*)(bp1 + kk);
        short8v b2 = *(const short8v*)(bp2 + kk);
        short8v b3 = *(const short8v*)(bp3 + kk);
        short8v af;
        af[0] = (short)f2bf(a0.x); af[1] = (short)f2bf(a0.y);
        af[2] = (short)f2bf(a0.z); af[3] = (short)f2bf(a0.w);
        af[4] = (short)f2bf(a1.x); af[5] = (short)f2bf(a1.y);
        af[6] = (short)f2bf(a1.z); af[7] = (short)f2bf(a1.w);
        acc0 = __builtin_amdgcn_mfma_f32_16x16x32_bf16(af, b0, acc0, 0, 0, 0);
        acc1 = __builtin_amdgcn_mfma_f32_16x16x32_bf16(af, b1, acc1, 0, 0, 0);
        acc2 = __builtin_amdgcn_mfma_f32_16x16x32_bf16(af, b2, acc2, 0, 0, 0);
        acc3 = __builtin_amdgcn_mfma_f32_16x16x32_bf16(af, b3, acc3, 0, 0, 0);
    }

    // C/D layout: col = lane&15, row = (lane>>4)*4 + reg  [m89 verified]
    const int rbase = blockIdx.x * 64 + w * 16 + ((l >> 4) << 2);
#pragma unroll
    for (int j = 0; j < 4; ++j) {
        float* vp = vnext + (size_t)(rbase + j) * DIM + lm;
        atomicAdd(vp +  0, acc0[j]);
        atomicAdd(vp + 16, acc1[j]);
        atomicAdd(vp + 32, acc2[j]);
        atomicAdd(vp + 48, acc3[j]);
    }
}

// ------ segment sum: out[m][d] = sum_{n: seg[n]==m} v[n][d]  (seg sorted) ------
__device__ __forceinline__ int lower_bound_dev(const int* __restrict__ seg, int val) {
    int lo = 0, hi = N_ATOMS;
    while (lo < hi) {
        int mid = (lo + hi) >> 1;
        if (seg[mid] < val) lo = mid + 1; else hi = mid;
    }
    return lo;
}

__global__ void segsum_kernel(const float* __restrict__ v,
                              const int* __restrict__ seg,
                              float* __restrict__ out) {
    int m = blockIdx.x;
    int d = threadIdx.x;  // 64
    int lo = lower_bound_dev(seg, m);
    int hi = lower_bound_dev(seg, m + 1);
    float acc = 0.f;
    for (int n = lo; n < hi; ++n) acc += v[n * DIM + d];
    out[m * DIM + d] = acc;
}

extern "C" void kernel_launch(void* const* d_in, const int* in_sizes, int n_in,
                              void* d_out, int out_size, void* d_ws, size_t ws_size,
                              hipStream_t stream) {
    const int*   fp    = (const int*)d_in[0];
    const float* A     = (const float*)d_in[1];
    const int*   seg   = (const int*)d_in[2];
    const float* table = (const float*)d_in[3];
    const float* W     = (const float*)d_in[4];
    const float* b     = (const float*)d_in[5];
    float* out = (float*)d_out;

    float*    v0 = (float*)d_ws;
    float*    v1 = v0 + (size_t)N_ATOMS * DIM;
    ushort_t* hT = (ushort_t*)(v1 + (size_t)N_ATOMS * DIM);

    embed_kernel<<<N_ATOMS, DIM, 0, stream>>>(fp, table, v0);

    float* vcur = v0;
    float* vnext = v1;
    for (int l = 0; l < N_LAYERS; ++l) {
        linear_relu_T_kernel<<<N_ATOMS / 64, 256, 0, stream>>>(
            vcur, W + l * DIM * DIM, b + l * DIM, vnext, hT);
        dim3 grid(N_ATOMS / 64, KS);
        matmul_mfma_kernel<<<grid, 256, 0, stream>>>(A, hT, vnext);
        float* tmp = vcur; vcur = vnext; vnext = tmp;
    }

    segsum_kernel<<<N_MOL, DIM, 0, stream>>>(vcur, seg, out);
}